// Round 4
// baseline (104.932 us; speedup 1.0000x reference)
//
#include <hip/hip_runtime.h>

// MoE block: B=128,K=32 -> N=4096 tokens, D=1024, H=256, E=32, top-1 routing.
// out[tok] = relu(relu(x[tok] @ W1[e] + b1[e]) @ W2[e] + b2[e]), e = argmax(x@rw.T+rb)
// 3 launches: fused_front (router blocks + weight-transpose blocks),
//             scan_scatter (histogram+tile list+order), moe_mlp (fused 2-layer MLP).

#define N_TOK 4096
#define DDIM  1024
#define HDIM  256
#define NEXP  32
#define MAXTILE 288   // >= sum_e ceil(ne/16) = 256 + 31

typedef __attribute__((ext_vector_type(8))) short bf16x8;   // 8 bf16 in 4 VGPRs
typedef __attribute__((ext_vector_type(4))) float f32x4;

__device__ __forceinline__ unsigned short f2bf(float f) {   // RNE f32->bf16
  union { float f; unsigned u; } v; v.f = f;
  unsigned r = v.u + 0x7FFFu + ((v.u >> 16) & 1u);
  return (unsigned short)(r >> 16);
}
__device__ __forceinline__ float bf2f(unsigned short h) {
  union { unsigned u; float f; } v; v.u = ((unsigned)h) << 16;
  return v.f;
}

// ---------------- K1: router blocks (0..255) + transpose blocks (256..2303) ----------------
// Router: 8 waves per 16-token tile, wave w owns K window [w*128,+128); fp32-accurate
// logits via 4-term bf16 hi/lo split MFMA (rw split in-block, rw is L2-resident);
// partials summed in LDS, wave 0 does bias + cross-lane argmax (first-index ties = np).
// Transpose: 64x64 f32 tiles through padded LDS, f2bf on store; 2 tiles per block.
__global__ __launch_bounds__(512) void fused_front_kernel(
    const float* __restrict__ x, const float* __restrict__ rw,
    const float* __restrict__ rb, const float* __restrict__ w1,
    const float* __restrict__ w2, unsigned short* __restrict__ xb,
    unsigned short* __restrict__ w1t, unsigned short* __restrict__ w2t,
    int* __restrict__ routed) {
  __shared__ float lds_f[4160];             // router red: 4096 f; transpose: 64x65 f
  int bid = blockIdx.x;
  int t = threadIdx.x;
  if (bid < 256) {
    int b = bid;                            // token tile of 16
    int w = t >> 6, l = t & 63;
    int m = l & 15, kb = l >> 4;
    int tok = b * 16 + m;
    int kbase = w * 128;
    bf16x8 wh[2][4], wl[2][4];              // rw rows m, m+16; this thread's k-window
#pragma unroll
    for (int h = 0; h < 2; h++) {
      const float* wp = rw + (size_t)(m + h * 16) * DDIM + kbase + kb * 8;
#pragma unroll
      for (int q = 0; q < 4; q++) {
        float4 f0 = *(const float4*)(wp + q * 32);
        float4 f1 = *(const float4*)(wp + q * 32 + 4);
        float fv[8] = {f0.x, f0.y, f0.z, f0.w, f1.x, f1.y, f1.z, f1.w};
        bf16x8 hi, lo;
#pragma unroll
        for (int i = 0; i < 8; i++) {
          unsigned short hh = f2bf(fv[i]);
          hi[i] = (short)hh;
          lo[i] = (short)f2bf(fv[i] - bf2f(hh));
        }
        wh[h][q] = hi; wl[h][q] = lo;
      }
    }
    const float* xrow = x + (size_t)tok * DDIM + kbase + kb * 8;
    unsigned short* xbrow = xb + (size_t)tok * DDIM + kbase + kb * 8;
    f32x4 acc0 = {0.f,0.f,0.f,0.f}, acc1 = {0.f,0.f,0.f,0.f};
#pragma unroll
    for (int q = 0; q < 4; q++) {
      float4 xa = *(const float4*)(xrow + q * 32);
      float4 xc = *(const float4*)(xrow + q * 32 + 4);
      float xv[8] = {xa.x, xa.y, xa.z, xa.w, xc.x, xc.y, xc.z, xc.w};
      bf16x8 xhi, xlo;
#pragma unroll
      for (int i = 0; i < 8; i++) {
        unsigned short hh = f2bf(xv[i]);
        xhi[i] = (short)hh;
        xlo[i] = (short)f2bf(xv[i] - bf2f(hh));
      }
      *(bf16x8*)(xbrow + q * 32) = xhi;     // xb written exactly once per (tok,k)
      acc0 = __builtin_amdgcn_mfma_f32_16x16x32_bf16(xhi, wh[0][q], acc0, 0, 0, 0);
      acc0 = __builtin_amdgcn_mfma_f32_16x16x32_bf16(xlo, wh[0][q], acc0, 0, 0, 0);
      acc0 = __builtin_amdgcn_mfma_f32_16x16x32_bf16(xhi, wl[0][q], acc0, 0, 0, 0);
      acc0 = __builtin_amdgcn_mfma_f32_16x16x32_bf16(xlo, wl[0][q], acc0, 0, 0, 0);
      acc1 = __builtin_amdgcn_mfma_f32_16x16x32_bf16(xhi, wh[1][q], acc1, 0, 0, 0);
      acc1 = __builtin_amdgcn_mfma_f32_16x16x32_bf16(xlo, wh[1][q], acc1, 0, 0, 0);
      acc1 = __builtin_amdgcn_mfma_f32_16x16x32_bf16(xhi, wl[1][q], acc1, 0, 0, 0);
      acc1 = __builtin_amdgcn_mfma_f32_16x16x32_bf16(xlo, wl[1][q], acc1, 0, 0, 0);
    }
    *(f32x4*)&lds_f[(w * 64 + l) * 8] = acc0;
    *(f32x4*)&lds_f[(w * 64 + l) * 8 + 4] = acc1;
    __syncthreads();
    if (w == 0) {
      f32x4 s0 = {0.f,0.f,0.f,0.f}, s1 = {0.f,0.f,0.f,0.f};
#pragma unroll
      for (int ww = 0; ww < 8; ww++) {
        s0 += *(const f32x4*)&lds_f[(ww * 64 + l) * 8];
        s1 += *(const f32x4*)&lds_f[(ww * 64 + l) * 8 + 4];
      }
      float rb0 = rb[m], rb1 = rb[16 + m];
#pragma unroll
      for (int r = 0; r < 4; r++) {         // token row = kb*4+r
        float v0 = s0[r] + rb0;
        float v1 = s1[r] + rb1;
        float val = v0; int idx = m;
        if (v1 > v0) { val = v1; idx = 16 + m; }   // ties -> smaller e (np.argmax)
#pragma unroll
        for (int s = 1; s < 16; s <<= 1) {
          float ov = __shfl_xor(val, s);
          int oi = __shfl_xor(idx, s);
          if (ov > val || (ov == val && oi < idx)) { val = ov; idx = oi; }
        }
        if (m == 0) routed[b * 16 + kb * 4 + r] = idx;
      }
    }
  } else {
    float (*tile)[65] = (float(*)[65])lds_f;
    int cl = t & 63, rl = t >> 6;           // 64 lanes contiguous in C: coalesced
    for (int sub = 0; sub < 2; sub++) {
      int tid = (bid - 256) * 2 + sub;      // 0..4095
      int mat = tid >> 11, within = tid & 2047;
      int e = within >> 6, tl = within & 63;
      const float* src; unsigned short* dst; int R, C, r0, c0;
      if (mat == 0) { src = w1; dst = w1t; R = 1024; C = 256;
                      r0 = (tl >> 2) * 64; c0 = (tl & 3) * 64; }
      else          { src = w2; dst = w2t; R = 256;  C = 1024;
                      r0 = (tl >> 4) * 64; c0 = (tl & 15) * 64; }
      const float* s = src + (size_t)e * R * C;
      unsigned short* d = dst + (size_t)e * R * C;
      if (sub) __syncthreads();             // LDS reuse across sub-tiles
#pragma unroll
      for (int i = 0; i < 8; i++)
        tile[i * 8 + rl][cl] = s[(size_t)(r0 + i * 8 + rl) * C + c0 + cl];
      __syncthreads();
#pragma unroll
      for (int i = 0; i < 8; i++)           // banks (cl + c)%32: conflict-free
        d[(size_t)(c0 + i * 8 + rl) * R + r0 + cl] = f2bf(tile[cl][i * 8 + rl]);
    }
  }
}

// ---------------- K2: histogram + scan + tile list + scatter (one block) ----------------
// tiles[i] = (e<<24) | (nrow<<16) | start_in_order ; meta[0] = n_tiles (16-token tiles)
__global__ __launch_bounds__(512) void scan_scatter_kernel(const int* __restrict__ routed,
    int* __restrict__ tiles, int* __restrict__ meta, int* __restrict__ order) {
  __shared__ int scnt[NEXP];
  __shared__ int scur[NEXP];
  int t = threadIdx.x;
  if (t < NEXP) scnt[t] = 0;
  __syncthreads();
  for (int n = t; n < N_TOK; n += 512) atomicAdd(&scnt[routed[n]], 1);
  __syncthreads();
  if (t < NEXP) {                           // lanes 0..31 of wave 0
    int c = scnt[t];
    int nt = (c + 15) >> 4;
    int ic = c, it = nt;                    // inclusive scans via shfl_up
#pragma unroll
    for (int s = 1; s < NEXP; s <<= 1) {
      int pc = __shfl_up(ic, s);
      int pt = __shfl_up(it, s);
      if (t >= s) { ic += pc; it += pt; }
    }
    int off = ic - c, tb = it - nt;
    scur[t] = off;
    for (int s = 0, ti = tb; s < c; s += 16, ti++) {
      int nr = c - s; if (nr > 16) nr = 16;
      tiles[ti] = (t << 24) | (nr << 16) | (off + s);
    }
    if (t == NEXP - 1) meta[0] = it;
  }
  __syncthreads();
  for (int n = t; n < N_TOK; n += 512) {
    int e = routed[n];
    int pos = atomicAdd(&scur[e], 1);       // intra-expert order arbitrary: out invariant
    order[pos] = n;
  }
}

// ---------------- K3: fused 2-layer expert MLP, one 16-token tile per block ----------------
// 8 waves. A (gathered xb rows) staged once in padded LDS (row stride 1032 -> 2-way max).
// B frags loaded DIRECT global->reg with 1-chunk prefetch (no LDS: zero intra-block B
// reuse; expert weights are L2/L3-resident). h kept in LDS (padded 264), then L2 layer.
// L1: wave w -> h cols [w*32,+32);  L2: wave w -> out cols [w*128,+128).
__global__ __launch_bounds__(512) void moe_mlp_kernel(
    const unsigned short* __restrict__ xb, const unsigned short* __restrict__ w1t,
    const float* __restrict__ b1, const unsigned short* __restrict__ w2t,
    const float* __restrict__ b2, const int* __restrict__ tiles,
    const int* __restrict__ meta, const int* __restrict__ order,
    float* __restrict__ out) {
  __shared__ unsigned short Al[16 * 1032];  // 33.0 KB
  __shared__ unsigned short Hl[16 * 264];   //  8.4 KB
  int ti = blockIdx.x;
  if (ti >= meta[0]) return;
  int info = tiles[ti];
  int e = info >> 24, nrow = (info >> 16) & 0xff, ts = info & 0xffff;
  int t = threadIdx.x, w = t >> 6, l = t & 63;
  int m = l & 15, kb = l >> 4;
  {                                         // stage A: 16 rows x 1024
    int ar = t >> 5, lc = t & 31;
    int tok = order[ts + (ar < nrow ? ar : nrow - 1)];   // clamp: masked at store
    const unsigned short* src = xb + (size_t)tok * DDIM + lc * 8;
    unsigned short* dst = &Al[ar * 1032 + lc * 8];
#pragma unroll
    for (int c = 0; c < 4; c++)
      *(bf16x8*)(dst + c * 256) = *(const bf16x8*)(src + c * 256);
  }
  // ---- L1: K=1024, 16 chunks of 64, B prefetched 1 chunk deep
  const unsigned short* bp0 = w1t + (size_t)e * (HDIM * DDIM) +
                              (size_t)(w * 32 + m) * DDIM + kb * 8;
  const unsigned short* bp1 = bp0 + 16 * DDIM;
  bf16x8 n00 = *(const bf16x8*)(bp0);
  bf16x8 n01 = *(const bf16x8*)(bp0 + 32);
  bf16x8 n10 = *(const bf16x8*)(bp1);
  bf16x8 n11 = *(const bf16x8*)(bp1 + 32);
  f32x4 acc0 = {0.f,0.f,0.f,0.f}, acc1 = {0.f,0.f,0.f,0.f};
  __syncthreads();                          // A visible
#pragma unroll 4
  for (int ck = 0; ck < 16; ck++) {
    bf16x8 c00 = n00, c01 = n01, c10 = n10, c11 = n11;
    if (ck + 1 < 16) {
      int ko = (ck + 1) * 64;
      n00 = *(const bf16x8*)(bp0 + ko);
      n01 = *(const bf16x8*)(bp0 + ko + 32);
      n10 = *(const bf16x8*)(bp1 + ko);
      n11 = *(const bf16x8*)(bp1 + ko + 32);
    }
    bf16x8 a0 = *(const bf16x8*)&Al[m * 1032 + ck * 64 + kb * 8];
    bf16x8 a1 = *(const bf16x8*)&Al[m * 1032 + ck * 64 + 32 + kb * 8];
    acc0 = __builtin_amdgcn_mfma_f32_16x16x32_bf16(a0, c00, acc0, 0, 0, 0);
    acc1 = __builtin_amdgcn_mfma_f32_16x16x32_bf16(a0, c10, acc1, 0, 0, 0);
    acc0 = __builtin_amdgcn_mfma_f32_16x16x32_bf16(a1, c01, acc0, 0, 0, 0);
    acc1 = __builtin_amdgcn_mfma_f32_16x16x32_bf16(a1, c11, acc1, 0, 0, 0);
  }
  {                                         // bias + relu -> Hl (bf16)
    float bz0 = b1[e * HDIM + w * 32 + m];
    float bz1 = b1[e * HDIM + w * 32 + 16 + m];
#pragma unroll
    for (int r = 0; r < 4; r++) {           // C/D: col=lane&15, row=kb*4+r
      int hr = kb * 4 + r;
      float v0 = acc0[r] + bz0; v0 = v0 > 0.f ? v0 : 0.f;
      float v1 = acc1[r] + bz1; v1 = v1 > 0.f ? v1 : 0.f;
      Hl[hr * 264 + w * 32 + m] = f2bf(v0);
      Hl[hr * 264 + w * 32 + 16 + m] = f2bf(v1);
    }
  }
  // ---- L2: K=256, 8 steps of 32, 8 col-frags per wave, B prefetched 1 step deep
  const unsigned short* cp = w2t + (size_t)e * (DDIM * HDIM) +
                             (size_t)(w * 128 + m) * HDIM + kb * 8;
  f32x4 qa[8];
  bf16x8 nb[8];
#pragma unroll
  for (int j = 0; j < 8; j++) {
    qa[j] = (f32x4){0.f,0.f,0.f,0.f};
    nb[j] = *(const bf16x8*)(cp + j * 16 * HDIM);
  }
  __syncthreads();                          // Hl visible
#pragma unroll
  for (int ks = 0; ks < 8; ks++) {
    bf16x8 cb[8];
#pragma unroll
    for (int j = 0; j < 8; j++) cb[j] = nb[j];
    if (ks + 1 < 8) {
#pragma unroll
      for (int j = 0; j < 8; j++)
        nb[j] = *(const bf16x8*)(cp + j * 16 * HDIM + (ks + 1) * 32);
    }
    bf16x8 a = *(const bf16x8*)&Hl[m * 264 + ks * 32 + kb * 8];
#pragma unroll
    for (int j = 0; j < 8; j++)
      qa[j] = __builtin_amdgcn_mfma_f32_16x16x32_bf16(a, cb[j], qa[j], 0, 0, 0);
  }
  float bw[8];
#pragma unroll
  for (int j = 0; j < 8; j++) bw[j] = b2[e * DDIM + w * 128 + j * 16 + m];
#pragma unroll
  for (int r = 0; r < 4; r++) {
    int crow = kb * 4 + r;
    if (crow < nrow) {
      int tok = order[ts + crow];
      float* op = out + (size_t)tok * DDIM + w * 128 + m;
#pragma unroll
      for (int j = 0; j < 8; j++) {
        float v = qa[j][r] + bw[j]; v = v > 0.f ? v : 0.f;
        op[j * 16] = v;
      }
    }
  }
}

// ---------------- launch ----------------

extern "C" void kernel_launch(void* const* d_in, const int* in_sizes, int n_in,
                              void* d_out, int out_size, void* d_ws, size_t ws_size,
                              hipStream_t stream) {
  const float* x  = (const float*)d_in[0];
  const float* rw = (const float*)d_in[1];
  const float* rb = (const float*)d_in[2];
  const float* w1 = (const float*)d_in[3];
  const float* b1 = (const float*)d_in[4];
  const float* w2 = (const float*)d_in[5];
  const float* b2 = (const float*)d_in[6];
  float* out = (float*)d_out;

  char* ws = (char*)d_ws;
  unsigned short* xb  = (unsigned short*)(ws + 0);          //  8,388,608  x bf16 [N][D]
  unsigned short* w1t = (unsigned short*)(ws + 8388608);    // 16,777,216  W1^T bf16 [E][H][D]
  unsigned short* w2t = (unsigned short*)(ws + 25165824);   // 16,777,216  W2^T bf16 [E][D][H]
  int* routed = (int*)(ws + 41943040);                      //     16,384
  int* order  = (int*)(ws + 41959424);                      //     16,384
  int* tiles  = (int*)(ws + 41975808);                      //      4,096 (MAXTILE ints)
  int* meta   = (int*)(ws + 41979904);                      //         64

  fused_front_kernel<<<dim3(2304), dim3(512), 0, stream>>>(
      x, rw, rb, w1, w2, xb, w1t, w2t, routed);
  scan_scatter_kernel<<<dim3(1), dim3(512), 0, stream>>>(routed, tiles, meta, order);
  moe_mlp_kernel<<<dim3(MAXTILE), dim3(512), 0, stream>>>(
      xb, w1t, b1, w2t, b2, tiles, meta, order, out);
}

// Round 5
// 70.681 us; speedup vs baseline: 1.4846x; 1.4846x over previous
//
#include <hip/hip_runtime.h>

// MoE block: B=128,K=32 -> N=4096 tokens, D=1024, H=256, E=32, top-1 routing.
// out[tok] = relu(relu(x[tok] @ W1[e] + b1[e]) @ W2[e] + b2[e]), e = argmax(x@rw.T+rb)
// 4 launches: fused_front (router + weight transpose), scan_scatter (tile list with
// XCD-pinned slots), expert_l1, expert_l2 (grouped GEMMs, full-A LDS, direct-global B).

#define N_TOK 4096
#define DDIM  1024
#define HDIM  256
#define NEXP  32
#define TPX   136          // max 32-token tiles per XCD class (<=132 worst case)
#define NSLOT (8 * TPX)    // 1088 block slots

typedef __attribute__((ext_vector_type(8))) short bf16x8;   // 8 bf16 in 4 VGPRs
typedef __attribute__((ext_vector_type(4))) float f32x4;

__device__ __forceinline__ unsigned short f2bf(float f) {   // RNE f32->bf16
  union { float f; unsigned u; } v; v.f = f;
  unsigned r = v.u + 0x7FFFu + ((v.u >> 16) & 1u);
  return (unsigned short)(r >> 16);
}
__device__ __forceinline__ float bf2f(unsigned short h) {
  union { unsigned u; float f; } v; v.u = ((unsigned)h) << 16;
  return v.f;
}

// ---------------- K1: router blocks (0..255) + transpose blocks (256..2303) ----------------
__global__ __launch_bounds__(512) void fused_front_kernel(
    const float* __restrict__ x, const float* __restrict__ rw,
    const float* __restrict__ rb, const float* __restrict__ w1,
    const float* __restrict__ w2, unsigned short* __restrict__ xb,
    unsigned short* __restrict__ w1t, unsigned short* __restrict__ w2t,
    int* __restrict__ routed) {
  __shared__ float lds_f[4160];             // router red: 4096 f; transpose: 64x65 f
  int bid = blockIdx.x;
  int t = threadIdx.x;
  if (bid < 256) {
    int b = bid;                            // token tile of 16
    int w = t >> 6, l = t & 63;
    int m = l & 15, kb = l >> 4;
    int tok = b * 16 + m;
    int kbase = w * 128;
    bf16x8 wh[2][4], wl[2][4];              // rw rows m, m+16; this thread's k-window
#pragma unroll
    for (int h = 0; h < 2; h++) {
      const float* wp = rw + (size_t)(m + h * 16) * DDIM + kbase + kb * 8;
#pragma unroll
      for (int q = 0; q < 4; q++) {
        float4 f0 = *(const float4*)(wp + q * 32);
        float4 f1 = *(const float4*)(wp + q * 32 + 4);
        float fv[8] = {f0.x, f0.y, f0.z, f0.w, f1.x, f1.y, f1.z, f1.w};
        bf16x8 hi, lo;
#pragma unroll
        for (int i = 0; i < 8; i++) {
          unsigned short hh = f2bf(fv[i]);
          hi[i] = (short)hh;
          lo[i] = (short)f2bf(fv[i] - bf2f(hh));
        }
        wh[h][q] = hi; wl[h][q] = lo;
      }
    }
    const float* xrow = x + (size_t)tok * DDIM + kbase + kb * 8;
    unsigned short* xbrow = xb + (size_t)tok * DDIM + kbase + kb * 8;
    f32x4 acc0 = {0.f,0.f,0.f,0.f}, acc1 = {0.f,0.f,0.f,0.f};
#pragma unroll
    for (int q = 0; q < 4; q++) {
      float4 xa = *(const float4*)(xrow + q * 32);
      float4 xc = *(const float4*)(xrow + q * 32 + 4);
      float xv[8] = {xa.x, xa.y, xa.z, xa.w, xc.x, xc.y, xc.z, xc.w};
      bf16x8 xhi, xlo;
#pragma unroll
      for (int i = 0; i < 8; i++) {
        unsigned short hh = f2bf(xv[i]);
        xhi[i] = (short)hh;
        xlo[i] = (short)f2bf(xv[i] - bf2f(hh));
      }
      *(bf16x8*)(xbrow + q * 32) = xhi;     // xb written exactly once per (tok,k)
      acc0 = __builtin_amdgcn_mfma_f32_16x16x32_bf16(xhi, wh[0][q], acc0, 0, 0, 0);
      acc0 = __builtin_amdgcn_mfma_f32_16x16x32_bf16(xlo, wh[0][q], acc0, 0, 0, 0);
      acc0 = __builtin_amdgcn_mfma_f32_16x16x32_bf16(xhi, wl[0][q], acc0, 0, 0, 0);
      acc0 = __builtin_amdgcn_mfma_f32_16x16x32_bf16(xlo, wl[0][q], acc0, 0, 0, 0);
      acc1 = __builtin_amdgcn_mfma_f32_16x16x32_bf16(xhi, wh[1][q], acc1, 0, 0, 0);
      acc1 = __builtin_amdgcn_mfma_f32_16x16x32_bf16(xlo, wh[1][q], acc1, 0, 0, 0);
      acc1 = __builtin_amdgcn_mfma_f32_16x16x32_bf16(xhi, wl[1][q], acc1, 0, 0, 0);
      acc1 = __builtin_amdgcn_mfma_f32_16x16x32_bf16(xlo, wl[1][q], acc1, 0, 0, 0);
    }
    *(f32x4*)&lds_f[(w * 64 + l) * 8] = acc0;
    *(f32x4*)&lds_f[(w * 64 + l) * 8 + 4] = acc1;
    __syncthreads();
    if (w == 0) {
      f32x4 s0 = {0.f,0.f,0.f,0.f}, s1 = {0.f,0.f,0.f,0.f};
#pragma unroll
      for (int ww = 0; ww < 8; ww++) {
        s0 += *(const f32x4*)&lds_f[(ww * 64 + l) * 8];
        s1 += *(const f32x4*)&lds_f[(ww * 64 + l) * 8 + 4];
      }
      float rb0 = rb[m], rb1 = rb[16 + m];
#pragma unroll
      for (int r = 0; r < 4; r++) {         // token row = kb*4+r
        float v0 = s0[r] + rb0;
        float v1 = s1[r] + rb1;
        float val = v0; int idx = m;
        if (v1 > v0) { val = v1; idx = 16 + m; }   // ties -> smaller e (np.argmax)
#pragma unroll
        for (int s = 1; s < 16; s <<= 1) {
          float ov = __shfl_xor(val, s);
          int oi = __shfl_xor(idx, s);
          if (ov > val || (ov == val && oi < idx)) { val = ov; idx = oi; }
        }
        if (m == 0) routed[b * 16 + kb * 4 + r] = idx;
      }
    }
  } else {
    float (*tile)[65] = (float(*)[65])lds_f;
    int cl = t & 63, rl = t >> 6;           // 64 lanes contiguous in C: coalesced
    for (int sub = 0; sub < 2; sub++) {
      int tid = (bid - 256) * 2 + sub;      // 0..4095
      int mat = tid >> 11, within = tid & 2047;
      int e = within >> 6, tl = within & 63;
      const float* src; unsigned short* dst; int R, C, r0, c0;
      if (mat == 0) { src = w1; dst = w1t; R = 1024; C = 256;
                      r0 = (tl >> 2) * 64; c0 = (tl & 3) * 64; }
      else          { src = w2; dst = w2t; R = 256;  C = 1024;
                      r0 = (tl >> 4) * 64; c0 = (tl & 15) * 64; }
      const float* s = src + (size_t)e * R * C;
      unsigned short* d = dst + (size_t)e * R * C;
      if (sub) __syncthreads();             // LDS reuse across sub-tiles
#pragma unroll
      for (int i = 0; i < 8; i++)
        tile[i * 8 + rl][cl] = s[(size_t)(r0 + i * 8 + rl) * C + c0 + cl];
      __syncthreads();
#pragma unroll
      for (int i = 0; i < 8; i++)           // banks (cl + c)%32: conflict-free
        d[(size_t)(c0 + i * 8 + rl) * R + r0 + cl] = f2bf(tile[cl][i * 8 + rl]);
    }
  }
}

// ---------------- K2: histogram + scan + XCD-pinned tile slots + scatter ----------------
// meta[0..7] = tiles per XCD class; meta[8 + slot] = (e<<24)|(nrow<<16)|start, where
// slot = (e&7) + 8*rank pins all tiles of expert e to one XCD (dispatch rr bid%8).
__global__ __launch_bounds__(512) void scan_scatter_kernel(const int* __restrict__ routed,
    int* __restrict__ meta, int* __restrict__ order) {
  __shared__ int scnt[NEXP];
  __shared__ int scur[NEXP];
  int t = threadIdx.x;
  if (t < NEXP) scnt[t] = 0;
  __syncthreads();
  for (int n = t; n < N_TOK; n += 512) atomicAdd(&scnt[routed[n]], 1);
  __syncthreads();
  if (t < NEXP) {                           // lanes 0..31 of wave 0
    int c = scnt[t];
    int nt = (c + 31) >> 5;                 // 32-token tiles
    int ic = c;                             // inclusive scan -> order offsets
#pragma unroll
    for (int s = 1; s < NEXP; s <<= 1) {
      int pc = __shfl_up(ic, s);
      if (t >= s) ic += pc;
    }
    int off = ic - c;
    scur[t] = off;
    int cls = t & 7, pos = t >> 3;          // XCD class, rank-in-class position
    int rank = 0;
#pragma unroll
    for (int j = 0; j < 4; j++) {
      int v = __shfl(nt, cls + j * 8);
      if (pos > j) rank += v;
    }
    for (int s2 = 0; s2 < nt; s2++) {
      int nr = c - s2 * 32; if (nr > 32) nr = 32;
      meta[8 + cls + 8 * (rank + s2)] = (t << 24) | (nr << 16) | (off + s2 * 32);
    }
    if (pos == 3) meta[cls] = rank + nt;    // per-class tile count
  }
  __syncthreads();
  for (int n = t; n < N_TOK; n += 512) {
    int e = routed[n];
    int p = atomicAdd(&scur[e], 1);         // intra-expert order arbitrary: out invariant
    order[p] = n;
  }
}

// ---------------- K3: L1 grouped GEMM: h = relu(xb @ W1[e] + b1[e]), K=1024 ----------------
// Block 512 thr = 8 waves, tile 32 tok x 128 cols (y of 2); wave = 32 tok x 16 cols.
// Full A (32x1024) staged once in LDS (stride 1040 shorts: conflict-free b128 both ways);
// B direct global->reg, 2-chunk prefetch; no barriers in K-loop.
__global__ __launch_bounds__(512) void expert_l1_kernel(
    const unsigned short* __restrict__ xb, const unsigned short* __restrict__ w1t,
    const float* __restrict__ b1, const int* __restrict__ meta,
    const int* __restrict__ order, unsigned short* __restrict__ hb) {
  __shared__ unsigned short Al[32 * 1040];  // 66.5 KB
  __shared__ int toks[32];
  int bid = blockIdx.x, xcd = bid & 7, idx = bid >> 3;
  if (idx >= meta[xcd]) return;
  int info = meta[8 + bid];
  int e = info >> 24, nrow = (info >> 16) & 0xff, ts = info & 0xffff;
  int t = threadIdx.x, w = t >> 6, l = t & 63, m = l & 15, kb = l >> 4;
  {                                         // stage A: 32 rows x 1024
    int ar = t >> 4, lc = t & 15;
    int tok = order[ts + (ar < nrow ? ar : nrow - 1)];   // clamp: masked at store
    if (lc == 0) toks[ar] = tok;
    const unsigned short* src = xb + (size_t)tok * DDIM + lc * 8;
    unsigned short* dst = Al + ar * 1040 + lc * 8;
#pragma unroll
    for (int p = 0; p < 8; p++)
      *(bf16x8*)(dst + p * 128) = *(const bf16x8*)(src + p * 128);
  }
  int col = blockIdx.y * 128 + w * 16 + m;
  const unsigned short* bp = w1t + (size_t)e * (HDIM * DDIM) + (size_t)col * DDIM + kb * 8;
  bf16x8 bq[2][2];
#pragma unroll
  for (int ck = 0; ck < 2; ck++) {
    bq[ck][0] = *(const bf16x8*)(bp + ck * 64);
    bq[ck][1] = *(const bf16x8*)(bp + ck * 64 + 32);
  }
  f32x4 acc0 = {0.f,0.f,0.f,0.f}, acc1 = {0.f,0.f,0.f,0.f};
  __syncthreads();                          // A visible; B prefetch stays in flight
#pragma unroll
  for (int ck = 0; ck < 16; ck++) {         // full unroll: bq indices compile-time
    bf16x8 c0 = bq[ck & 1][0], c1 = bq[ck & 1][1];
    if (ck + 2 < 16) {
      bq[ck & 1][0] = *(const bf16x8*)(bp + (ck + 2) * 64);
      bq[ck & 1][1] = *(const bf16x8*)(bp + (ck + 2) * 64 + 32);
    }
    const unsigned short* ap = Al + m * 1040 + ck * 64 + kb * 8;
    bf16x8 a00 = *(const bf16x8*)(ap);
    bf16x8 a01 = *(const bf16x8*)(ap + 32);
    bf16x8 a10 = *(const bf16x8*)(ap + 16 * 1040);
    bf16x8 a11 = *(const bf16x8*)(ap + 16 * 1040 + 32);
    acc0 = __builtin_amdgcn_mfma_f32_16x16x32_bf16(a00, c0, acc0, 0, 0, 0);
    acc0 = __builtin_amdgcn_mfma_f32_16x16x32_bf16(a01, c1, acc0, 0, 0, 0);
    acc1 = __builtin_amdgcn_mfma_f32_16x16x32_bf16(a10, c0, acc1, 0, 0, 0);
    acc1 = __builtin_amdgcn_mfma_f32_16x16x32_bf16(a11, c1, acc1, 0, 0, 0);
  }
  float bias = b1[e * HDIM + col];
#pragma unroll
  for (int r = 0; r < 4; r++) {             // C/D: col=lane&15, row=kb*4+r (+16)
    int r0 = kb * 4 + r;
    if (r0 < nrow) {
      float v = acc0[r] + bias; v = v > 0.f ? v : 0.f;
      hb[(size_t)toks[r0] * HDIM + col] = f2bf(v);
    }
    int r1 = 16 + kb * 4 + r;
    if (r1 < nrow) {
      float v = acc1[r] + bias; v = v > 0.f ? v : 0.f;
      hb[(size_t)toks[r1] * HDIM + col] = f2bf(v);
    }
  }
}

// ---------------- K4: L2 grouped GEMM: out = relu(h @ W2[e] + b2[e]), K=256 ----------------
// Block 512 thr = 8 waves, tile 32 tok x 256 cols (y of 4); wave = 32 tok x 32 cols.
__global__ __launch_bounds__(512) void expert_l2_kernel(
    const unsigned short* __restrict__ hb, const unsigned short* __restrict__ w2t,
    const float* __restrict__ b2, const int* __restrict__ meta,
    const int* __restrict__ order, float* __restrict__ out) {
  __shared__ unsigned short Hl[32 * 272];   // 17.4 KB, stride 272: conflict-free
  __shared__ int toks[32];
  int bid = blockIdx.x, xcd = bid & 7, idx = bid >> 3;
  if (idx >= meta[xcd]) return;
  int info = meta[8 + bid];
  int e = info >> 24, nrow = (info >> 16) & 0xff, ts = info & 0xffff;
  int t = threadIdx.x, w = t >> 6, l = t & 63, m = l & 15, kb = l >> 4;
  {                                         // stage h: 32 rows x 256
    int ar = t >> 4, lc = t & 15;
    int tok = order[ts + (ar < nrow ? ar : nrow - 1)];
    if (lc == 0) toks[ar] = tok;
    const unsigned short* src = hb + (size_t)tok * HDIM + lc * 8;
    unsigned short* dst = Hl + ar * 272 + lc * 8;
#pragma unroll
    for (int p = 0; p < 2; p++)
      *(bf16x8*)(dst + p * 128) = *(const bf16x8*)(src + p * 128);
  }
  int c0 = blockIdx.y * 256 + w * 32 + m;   // second col group at c0+16
  const unsigned short* bp0 = w2t + (size_t)e * (DDIM * HDIM) + (size_t)c0 * HDIM + kb * 8;
  const unsigned short* bp1 = bp0 + 16 * HDIM;
  bf16x8 bq[2][4];
#pragma unroll
  for (int ck = 0; ck < 2; ck++) {
    bq[ck][0] = *(const bf16x8*)(bp0 + ck * 64);
    bq[ck][1] = *(const bf16x8*)(bp0 + ck * 64 + 32);
    bq[ck][2] = *(const bf16x8*)(bp1 + ck * 64);
    bq[ck][3] = *(const bf16x8*)(bp1 + ck * 64 + 32);
  }
  f32x4 acc00 = {0.f,0.f,0.f,0.f}, acc01 = acc00, acc10 = acc00, acc11 = acc00;
  __syncthreads();
#pragma unroll
  for (int ck = 0; ck < 4; ck++) {
    bf16x8 d0 = bq[ck & 1][0], d1 = bq[ck & 1][1];
    bf16x8 d2 = bq[ck & 1][2], d3 = bq[ck & 1][3];
    if (ck + 2 < 4) {
      bq[ck & 1][0] = *(const bf16x8*)(bp0 + (ck + 2) * 64);
      bq[ck & 1][1] = *(const bf16x8*)(bp0 + (ck + 2) * 64 + 32);
      bq[ck & 1][2] = *(const bf16x8*)(bp1 + (ck + 2) * 64);
      bq[ck & 1][3] = *(const bf16x8*)(bp1 + (ck + 2) * 64 + 32);
    }
    const unsigned short* ap = Hl + m * 272 + ck * 64 + kb * 8;
    bf16x8 a00 = *(const bf16x8*)(ap);
    bf16x8 a01 = *(const bf16x8*)(ap + 32);
    bf16x8 a10 = *(const bf16x8*)(ap + 16 * 272);
    bf16x8 a11 = *(const bf16x8*)(ap + 16 * 272 + 32);
    acc00 = __builtin_amdgcn_mfma_f32_16x16x32_bf16(a00, d0, acc00, 0, 0, 0);
    acc00 = __builtin_amdgcn_mfma_f32_16x16x32_bf16(a01, d1, acc00, 0, 0, 0);
    acc01 = __builtin_amdgcn_mfma_f32_16x16x32_bf16(a00, d2, acc01, 0, 0, 0);
    acc01 = __builtin_amdgcn_mfma_f32_16x16x32_bf16(a01, d3, acc01, 0, 0, 0);
    acc10 = __builtin_amdgcn_mfma_f32_16x16x32_bf16(a10, d0, acc10, 0, 0, 0);
    acc10 = __builtin_amdgcn_mfma_f32_16x16x32_bf16(a11, d1, acc10, 0, 0, 0);
    acc11 = __builtin_amdgcn_mfma_f32_16x16x32_bf16(a10, d2, acc11, 0, 0, 0);
    acc11 = __builtin_amdgcn_mfma_f32_16x16x32_bf16(a11, d3, acc11, 0, 0, 0);
  }
  float bias0 = b2[e * DDIM + c0], bias1 = b2[e * DDIM + c0 + 16];
#pragma unroll
  for (int r = 0; r < 4; r++) {
    int r0 = kb * 4 + r;
    if (r0 < nrow) {
      float* op = out + (size_t)toks[r0] * DDIM;
      float v0 = acc00[r] + bias0; op[c0]      = v0 > 0.f ? v0 : 0.f;
      float v1 = acc01[r] + bias1; op[c0 + 16] = v1 > 0.f ? v1 : 0.f;
    }
    int r1 = 16 + kb * 4 + r;
    if (r1 < nrow) {
      float* op = out + (size_t)toks[r1] * DDIM;
      float v0 = acc10[r] + bias0; op[c0]      = v0 > 0.f ? v0 : 0.f;
      float v1 = acc11[r] + bias1; op[c0 + 16] = v1 > 0.f ? v1 : 0.f;
    }
  }
}

// ---------------- launch ----------------

extern "C" void kernel_launch(void* const* d_in, const int* in_sizes, int n_in,
                              void* d_out, int out_size, void* d_ws, size_t ws_size,
                              hipStream_t stream) {
  const float* x  = (const float*)d_in[0];
  const float* rw = (const float*)d_in[1];
  const float* rb = (const float*)d_in[2];
  const float* w1 = (const float*)d_in[3];
  const float* b1 = (const float*)d_in[4];
  const float* w2 = (const float*)d_in[5];
  const float* b2 = (const float*)d_in[6];
  float* out = (float*)d_out;

  char* ws = (char*)d_ws;
  unsigned short* xb  = (unsigned short*)(ws + 0);          //  8,388,608  x bf16 [N][D]
  unsigned short* w1t = (unsigned short*)(ws + 8388608);    // 16,777,216  W1^T bf16 [E][H][D]
  unsigned short* w2t = (unsigned short*)(ws + 25165824);   // 16,777,216  W2^T bf16 [E][D][H]
  unsigned short* hb  = (unsigned short*)(ws + 41943040);   //  2,097,152  h bf16 [N][H]
  int* routed = (int*)(ws + 44040192);                      //     16,384
  int* order  = (int*)(ws + 44056576);                      //     16,384
  int* meta   = (int*)(ws + 44072960);                      //  (8+NSLOT)*4 = 4,384

  fused_front_kernel<<<dim3(2304), dim3(512), 0, stream>>>(
      x, rw, rb, w1, w2, xb, w1t, w2t, routed);
  scan_scatter_kernel<<<dim3(1), dim3(512), 0, stream>>>(routed, meta, order);
  expert_l1_kernel<<<dim3(NSLOT, 2), dim3(512), 0, stream>>>(
      xb, w1t, b1, meta, order, hb);
  expert_l2_kernel<<<dim3(NSLOT, 4), dim3(512), 0, stream>>>(
      hb, w2t, b2, meta, order, out);
}

// Round 6
// 62.033 us; speedup vs baseline: 1.6916x; 1.1394x over previous
//
#include <hip/hip_runtime.h>

// MoE block: B=128,K=32 -> N=4096 tokens, D=1024, H=256, E=32, top-1 routing.
// out[tok] = relu(relu(x[tok] @ W1[e] + b1[e]) @ W2[e] + b2[e]), e = argmax(x@rw.T+rb)
// 4 launches: router, scan_scatter, expert_gemm<L1>, expert_gemm<L2>.
// Weights are consumed in ORIGINAL fp32 [K][N] layout; transpose+bf16-cvt happens
// in-kernel during LDS staging (no pre-transposed weight copies, no xb copy).

#define N_TOK 4096
#define DDIM  1024
#define HDIM  256
#define NEXP  32
#define TPX   136          // max 32-token tiles per XCD class (<=132 worst case)
#define NSLOT (8 * TPX)    // 1088 block slots

typedef __attribute__((ext_vector_type(8))) short bf16x8;   // 8 bf16 in 4 VGPRs
typedef __attribute__((ext_vector_type(4))) float f32x4;

__device__ __forceinline__ unsigned short f2bf(float f) {   // RNE f32->bf16
  union { float f; unsigned u; } v; v.f = f;
  unsigned r = v.u + 0x7FFFu + ((v.u >> 16) & 1u);
  return (unsigned short)(r >> 16);
}
__device__ __forceinline__ float bf2f(unsigned short h) {
  union { unsigned u; float f; } v; v.u = ((unsigned)h) << 16;
  return v.f;
}
// LDS tile addressing: row-major stride 72 shorts, kk bits 3-5 XORed with (row>>3)&7.
// Conflict-free-floor for b128 frag reads, b32/b64 staging writes (derivation in notes).
__device__ __forceinline__ int swz(int row, int kk) {
  return row * 72 + (kk ^ (((row >> 3) & 7) << 3));
}

// ---------------- K1: router (fp32-accurate logits via 4-term bf16 split MFMA) --------
// 512 thr = 8 waves per 16-token tile; wave w owns K window [w*128,+128).
__global__ __launch_bounds__(512) void router_kernel(
    const float* __restrict__ x, const float* __restrict__ rw,
    const float* __restrict__ rb, int* __restrict__ routed) {
  __shared__ float red[8][64][8];
  int b = blockIdx.x;
  int t = threadIdx.x, w = t >> 6, l = t & 63;
  int m = l & 15, kb = l >> 4;
  int tok = b * 16 + m;
  int kbase = w * 128;
  bf16x8 wh[2][4], wl[2][4];              // rw rows m, m+16; this thread's k-window
#pragma unroll
  for (int h = 0; h < 2; h++) {
    const float* wp = rw + (size_t)(m + h * 16) * DDIM + kbase + kb * 8;
#pragma unroll
    for (int q = 0; q < 4; q++) {
      float4 f0 = *(const float4*)(wp + q * 32);
      float4 f1 = *(const float4*)(wp + q * 32 + 4);
      float fv[8] = {f0.x, f0.y, f0.z, f0.w, f1.x, f1.y, f1.z, f1.w};
      bf16x8 hi, lo;
#pragma unroll
      for (int i = 0; i < 8; i++) {
        unsigned short hh = f2bf(fv[i]);
        hi[i] = (short)hh;
        lo[i] = (short)f2bf(fv[i] - bf2f(hh));
      }
      wh[h][q] = hi; wl[h][q] = lo;
    }
  }
  const float* xrow = x + (size_t)tok * DDIM + kbase + kb * 8;
  f32x4 acc0 = {0.f,0.f,0.f,0.f}, acc1 = {0.f,0.f,0.f,0.f};
#pragma unroll
  for (int q = 0; q < 4; q++) {
    float4 xa = *(const float4*)(xrow + q * 32);
    float4 xc = *(const float4*)(xrow + q * 32 + 4);
    float xv[8] = {xa.x, xa.y, xa.z, xa.w, xc.x, xc.y, xc.z, xc.w};
    bf16x8 xhi, xlo;
#pragma unroll
    for (int i = 0; i < 8; i++) {
      unsigned short hh = f2bf(xv[i]);
      xhi[i] = (short)hh;
      xlo[i] = (short)f2bf(xv[i] - bf2f(hh));
    }
    acc0 = __builtin_amdgcn_mfma_f32_16x16x32_bf16(xhi, wh[0][q], acc0, 0, 0, 0);
    acc0 = __builtin_amdgcn_mfma_f32_16x16x32_bf16(xlo, wh[0][q], acc0, 0, 0, 0);
    acc0 = __builtin_amdgcn_mfma_f32_16x16x32_bf16(xhi, wl[0][q], acc0, 0, 0, 0);
    acc0 = __builtin_amdgcn_mfma_f32_16x16x32_bf16(xlo, wl[0][q], acc0, 0, 0, 0);
    acc1 = __builtin_amdgcn_mfma_f32_16x16x32_bf16(xhi, wh[1][q], acc1, 0, 0, 0);
    acc1 = __builtin_amdgcn_mfma_f32_16x16x32_bf16(xlo, wh[1][q], acc1, 0, 0, 0);
    acc1 = __builtin_amdgcn_mfma_f32_16x16x32_bf16(xhi, wl[1][q], acc1, 0, 0, 0);
    acc1 = __builtin_amdgcn_mfma_f32_16x16x32_bf16(xlo, wl[1][q], acc1, 0, 0, 0);
  }
  *(f32x4*)&red[w][l][0] = acc0;
  *(f32x4*)&red[w][l][4] = acc1;
  __syncthreads();
  if (w == 0) {
    f32x4 s0 = {0.f,0.f,0.f,0.f}, s1 = {0.f,0.f,0.f,0.f};
#pragma unroll
    for (int ww = 0; ww < 8; ww++) {
      s0 += *(const f32x4*)&red[ww][l][0];
      s1 += *(const f32x4*)&red[ww][l][4];
    }
    float rb0 = rb[m], rb1 = rb[16 + m];
#pragma unroll
    for (int r = 0; r < 4; r++) {       // token row = kb*4+r
      float v0 = s0[r] + rb0;
      float v1 = s1[r] + rb1;
      float val = v0; int idx = m;
      if (v1 > v0) { val = v1; idx = 16 + m; }   // ties -> smaller e (np.argmax)
#pragma unroll
      for (int s = 1; s < 16; s <<= 1) {
        float ov = __shfl_xor(val, s);
        int oi = __shfl_xor(idx, s);
        if (ov > val || (ov == val && oi < idx)) { val = ov; idx = oi; }
      }
      if (m == 0) routed[b * 16 + kb * 4 + r] = idx;
    }
  }
}

// ---------------- K2: histogram + scan + XCD-pinned tile slots + scatter --------------
// meta[0..7] = tiles per XCD class; meta[8 + slot] = (e<<24)|(nrow<<16)|start, where
// slot = (e&7) + 8*rank pins all tiles of expert e to one XCD (dispatch rr bid%8).
__global__ __launch_bounds__(512) void scan_scatter_kernel(const int* __restrict__ routed,
    int* __restrict__ meta, int* __restrict__ order) {
  __shared__ int scnt[NEXP];
  __shared__ int scur[NEXP];
  int t = threadIdx.x;
  if (t < NEXP) scnt[t] = 0;
  __syncthreads();
  for (int n = t; n < N_TOK; n += 512) atomicAdd(&scnt[routed[n]], 1);
  __syncthreads();
  if (t < NEXP) {                           // lanes 0..31 of wave 0
    int c = scnt[t];
    int nt = (c + 31) >> 5;                 // 32-token tiles
    int ic = c;
#pragma unroll
    for (int s = 1; s < NEXP; s <<= 1) {
      int pc = __shfl_up(ic, s);
      if (t >= s) ic += pc;
    }
    int off = ic - c;
    scur[t] = off;
    int cls = t & 7, pos = t >> 3;          // XCD class, rank-in-class position
    int rank = 0;
#pragma unroll
    for (int j = 0; j < 4; j++) {
      int v = __shfl(nt, cls + j * 8);
      if (pos > j) rank += v;
    }
    for (int s2 = 0; s2 < nt; s2++) {
      int nr = c - s2 * 32; if (nr > 32) nr = 32;
      meta[8 + cls + 8 * (rank + s2)] = (t << 24) | (nr << 16) | (off + s2 * 32);
    }
    if (pos == 3) meta[cls] = rank + nt;    // per-class tile count
  }
  __syncthreads();
  for (int n = t; n < N_TOK; n += 512) {
    int e = routed[n];
    int p = atomicAdd(&scur[e], 1);         // intra-expert order arbitrary: out invariant
    order[p] = n;
  }
}

// ---------------- K3/K4: grouped GEMM with in-LDS transpose of fp32 weights ----------
// Block 512 thr = 8 waves, tile 32 tok x 128 cols; per 64-k chunk: stage A (gathered
// rows, fp32->bf16 for L1) and B (W[k][n] fp32 -> bf16 transposed) into swizzled LDS,
// double-buffered; one barrier per chunk; next chunk's global loads fly under MFMA.
template <int KDIM, int NTOT, bool A_FP32, bool OUT_BF16>
__global__ __launch_bounds__(512) void expert_gemm_kernel(
    const void* __restrict__ a_src, const float* __restrict__ wsrc,
    const float* __restrict__ bias, const int* __restrict__ meta,
    const int* __restrict__ order, void* __restrict__ outp) {
  constexpr int NCH = KDIM / 64;
  __shared__ unsigned short AT[2][32 * 72];   //  9.2 KB
  __shared__ unsigned short BT[2][128 * 72];  // 36.9 KB
  int bid = blockIdx.x, xcd = bid & 7, idx = bid >> 3;
  if (idx >= meta[xcd]) return;
  int info = meta[8 + bid];
  int e = info >> 24, nrow = (info >> 16) & 0xff, ts = info & 0xffff;
  int c0 = blockIdx.y * 128;
  int t = threadIdx.x, w = t >> 6, l = t & 63, m = l & 15, kb = l >> 4;
  // staging roles: A = 32 rows x 64 kk (thread: row=t>>4, kk=(t&15)*4, b64);
  //                B = 128 cn  x 64 kk (thread: cn=t&127, kgroup=t>>7, 8 k-pairs)
  int atr = t >> 4, ak4 = (t & 15) * 4;
  int bcn = t & 127, bkg = t >> 7;
  int atok = order[ts + (atr < nrow ? atr : nrow - 1)];   // clamp: masked at store
  const float* aF = (const float*)a_src + (size_t)atok * KDIM + ak4;
  const unsigned short* aH = (const unsigned short*)a_src + (size_t)atok * KDIM + ak4;
  const float* bS = wsrc + (size_t)e * KDIM * NTOT + (size_t)(bkg * 16) * NTOT + c0 + bcn;

  float4 nAf; ushort4 nAh;
  float nB[16];
  auto LOADC = [&](int c) {
    if constexpr (A_FP32) nAf = *(const float4*)(aF + c * 64);
    else                  nAh = *(const ushort4*)(aH + c * 64);
#pragma unroll
    for (int j = 0; j < 8; j++) {
      nB[2*j]   = bS[(size_t)(c * 64 + 2*j) * NTOT];
      nB[2*j+1] = bS[(size_t)(c * 64 + 2*j + 1) * NTOT];
    }
  };

  f32x4 acc0 = {0.f,0.f,0.f,0.f}, acc1 = {0.f,0.f,0.f,0.f};
  LOADC(0);
  for (int c = 0; c < NCH; c++) {
    int p = c & 1;
    ushort4 av;                               // copy out current chunk regs
    if constexpr (A_FP32) {
      av.x = f2bf(nAf.x); av.y = f2bf(nAf.y); av.z = f2bf(nAf.z); av.w = f2bf(nAf.w);
    } else av = nAh;
    float cB[16];
#pragma unroll
    for (int j = 0; j < 16; j++) cB[j] = nB[j];
    if (c + 1 < NCH) LOADC(c + 1);            // next chunk flies under writes+MFMA
    *(ushort4*)&AT[p][swz(atr, ak4)] = av;
#pragma unroll
    for (int j = 0; j < 8; j++) {
      ushort2 pk; pk.x = f2bf(cB[2*j]); pk.y = f2bf(cB[2*j+1]);
      *(ushort2*)&BT[p][swz(bcn, bkg * 16 + 2*j)] = pk;
    }
    asm volatile("s_waitcnt lgkmcnt(0)" ::: "memory");   // writes visible
    __builtin_amdgcn_s_barrier();                        // vmcnt stays in flight
#pragma unroll
    for (int ks = 0; ks < 2; ks++) {
      int kk = ks * 32 + kb * 8;
      bf16x8 bfr = *(const bf16x8*)&BT[p][swz(w * 16 + m, kk)];
      bf16x8 a0  = *(const bf16x8*)&AT[p][swz(m, kk)];
      bf16x8 a1  = *(const bf16x8*)&AT[p][swz(16 + m, kk)];
      acc0 = __builtin_amdgcn_mfma_f32_16x16x32_bf16(a0, bfr, acc0, 0, 0, 0);
      acc1 = __builtin_amdgcn_mfma_f32_16x16x32_bf16(a1, bfr, acc1, 0, 0, 0);
    }
    // reads of BT/AT[p] retire before this wave's next-iter writes (other buffer);
    // buffer p is rewritten only after the NEXT barrier -> safe with one barrier.
  }
  int col = c0 + w * 16 + m;
  float bz = bias[e * NTOT + col];
#pragma unroll
  for (int r = 0; r < 4; r++) {               // C/D: col=lane&15, row=kb*4+r (+16)
    int r0 = kb * 4 + r;
    if (r0 < nrow) {
      int tok = order[ts + r0];
      float v = acc0[r] + bz; v = v > 0.f ? v : 0.f;
      if constexpr (OUT_BF16)
        ((unsigned short*)outp)[(size_t)tok * NTOT + col] = f2bf(v);
      else
        ((float*)outp)[(size_t)tok * NTOT + col] = v;
    }
    int r1 = 16 + kb * 4 + r;
    if (r1 < nrow) {
      int tok = order[ts + r1];
      float v = acc1[r] + bz; v = v > 0.f ? v : 0.f;
      if constexpr (OUT_BF16)
        ((unsigned short*)outp)[(size_t)tok * NTOT + col] = f2bf(v);
      else
        ((float*)outp)[(size_t)tok * NTOT + col] = v;
    }
  }
}

// ---------------- launch ----------------

extern "C" void kernel_launch(void* const* d_in, const int* in_sizes, int n_in,
                              void* d_out, int out_size, void* d_ws, size_t ws_size,
                              hipStream_t stream) {
  const float* x  = (const float*)d_in[0];
  const float* rw = (const float*)d_in[1];
  const float* rb = (const float*)d_in[2];
  const float* w1 = (const float*)d_in[3];
  const float* b1 = (const float*)d_in[4];
  const float* w2 = (const float*)d_in[5];
  const float* b2 = (const float*)d_in[6];
  float* out = (float*)d_out;

  char* ws = (char*)d_ws;
  unsigned short* hb = (unsigned short*)(ws + 0);   // 2,097,152  h bf16 [N][H]
  int* routed = (int*)(ws + 2097152);               //    16,384
  int* order  = (int*)(ws + 2113536);               //    16,384
  int* meta   = (int*)(ws + 2129920);               //    (8+NSLOT)*4

  router_kernel<<<dim3(256), dim3(512), 0, stream>>>(x, rw, rb, routed);
  scan_scatter_kernel<<<dim3(1), dim3(512), 0, stream>>>(routed, meta, order);
  expert_gemm_kernel<DDIM, HDIM, true, true><<<dim3(NSLOT, 2), dim3(512), 0, stream>>>(
      x, w1, b1, meta, order, hb);
  expert_gemm_kernel<HDIM, DDIM, false, false><<<dim3(NSLOT, 8), dim3(512), 0, stream>>>(
      hb, w2, b2, meta, order, out);
}